// Round 14
// baseline (179.723 us; speedup 1.0000x reference)
//
#include <hip/hip_runtime.h>

#define DIM 768
#define NHEADS 12
#define HDIM 64
#define BATCH 2
#define SEQ 2048
#define ROWS (BATCH*SEQ)   // 4096
#define KSPLIT 4

typedef __attribute__((ext_vector_type(8))) _Float16 f16x8;
typedef __attribute__((ext_vector_type(4))) _Float16 f16x4;
typedef __attribute__((ext_vector_type(2))) _Float16 f16x2;
typedef __attribute__((ext_vector_type(4))) float    f32x4;

// async global->LDS DMA, 16 B per lane; LDS dest must be wave-uniform base
__device__ __forceinline__ void dma16(const _Float16* g, _Float16* l) {
    __builtin_amdgcn_global_load_lds(
        (const __attribute__((address_space(1))) unsigned int*)g,
        (__attribute__((address_space(3))) unsigned int*)l, 16, 0, 0);
}

// ============================================================
// Fragment layout F(mt, kt): 16 rows x 32 cols of row-major M[R][C]:
//   frag[lane][j] = M[mt*16 + (lane&15)][kt*32 + (lane>>4)*8 + j]
// stored at dst[((mt*(C/32) + kt)*64 + lane)*8] (halves).
// V tile layout (for 16x16x16 PV MFMA): per 16-key chunk kc,
//   Vkt[((kc*48 + (h*4+dt))*64 + lane)*4] : tile[lane][j] =
//   V[d = (h*4+dt)*16 + (lane&15)][key = kc*16 + (lane>>4)*4 + j]
// ============================================================

// ---- all 4 fp32->f16 frag conversions in one launch (all have C=768) ----
// Wq is pre-scaled by log2(e): QK^T scores land in log2 domain, so the
// softmax exp is a single v_exp_f32 (2^x). Wq feeds ONLY Q. (verified v4/v5)
__global__ __launch_bounds__(256) void cvt_all(
    const float* __restrict__ x,  const float* __restrict__ wq,
    const float* __restrict__ wk, const float* __restrict__ wv,
    _Float16* __restrict__ xf,  _Float16* __restrict__ wqf,
    _Float16* __restrict__ wkf, _Float16* __restrict__ wvf)
{
    const int lane = threadIdx.x & 63;
    const int wid  = (blockIdx.x * 256 + threadIdx.x) >> 6;
    const float* src; _Float16* dst; int t;
    float sc = 1.0f;
    if (wid < 6144)      { src = x;  dst = xf;  t = wid;        }
    else if (wid < 7296) { src = wq; dst = wqf; t = wid - 6144; sc = 1.4426950408889634f; }
    else if (wid < 8448) { src = wk; dst = wkf; t = wid - 7296; }
    else                 { src = wv; dst = wvf; t = wid - 8448; }
    const int c = lane & 15, quad = lane >> 4;
    const int mt = t / 24, kt = t % 24;
    const float* p = src + (size_t)(mt*16 + c) * 768 + kt*32 + quad*8;
    float4 v0 = *(const float4*)p;
    float4 v1 = *(const float4*)(p + 4);
    f16x8 o;
    o[0]=(_Float16)(v0.x*sc); o[1]=(_Float16)(v0.y*sc); o[2]=(_Float16)(v0.z*sc); o[3]=(_Float16)(v0.w*sc);
    o[4]=(_Float16)(v1.x*sc); o[5]=(_Float16)(v1.y*sc); o[6]=(_Float16)(v1.z*sc); o[7]=(_Float16)(v1.w*sc);
    *reinterpret_cast<f16x8*>(dst + ((size_t)t * 64 + lane) * 8) = o;
}

// ---- all 3 projections: 256x128 tiles, 8 waves, 288 blocks ----
// v12 (kept, non-negative): 3-deep staging + counted vmcnt(3) barriers (T4).
// Iteration k stages tile k+2 and waits vmcnt(3): tile k+1 guaranteed
// complete (per-wave FIFO; barrier makes it cross-wave), tile k+2 stays IN
// FLIGHT across the barrier with a full iteration of latency cover.
// LDS 72 KB -> still 2 blocks/CU.
// bid < 192: C = x * [Wq;Wk]^T  (M=4096, N=1536) -> Qf/Kf frag layout
// bid >= 192: C = Wv * x^T      (M=768, N=4096)  -> Vkt 16x16 tile layout
__global__ __launch_bounds__(512) void gemm3(
    const _Float16* __restrict__ xf, const _Float16* __restrict__ wqkf,
    const _Float16* __restrict__ wvf,
    _Float16* __restrict__ Qf, _Float16* __restrict__ Kf, _Float16* __restrict__ Vkt)
{
    __shared__ _Float16 Ab[3][16*512];   // 48 KB (A: 16 row-units, 3-deep)
    __shared__ _Float16 Bb[3][8*512];    // 24 KB (B: 8 col-units, 3-deep)
    const int tid = threadIdx.x, lane = tid & 63, w = tid >> 6;
    const int c = lane & 15, quad = lane >> 4;

    const _Float16 *Af, *Bf;
    int mt0, nt0, mode;
    if ((int)blockIdx.x < 192) {
        int mt = blockIdx.x / 12, nt = blockIdx.x % 12;   // 16x12 tiles
        Af = xf; Bf = wqkf; mt0 = mt*16; nt0 = nt*8; mode = 0;
    } else {
        int v = blockIdx.x - 192;
        int mt = v / 32, nt = v % 32;                     // 3x32 tiles
        Af = wvf; Bf = xf; mt0 = mt*16; nt0 = nt*8; mode = 1;
    }

    auto stage = [&](int kt, int buf) {
#pragma unroll
        for (int u = 0; u < 3; ++u) {
            const int cc = w*3 + u;   // 0..23: 16 A-units then 8 B-units
            const _Float16* s = (cc < 16) ? Af + ((size_t)(mt0+cc)*24 + kt)*512
                                          : Bf + ((size_t)(nt0+cc-16)*24 + kt)*512;
            _Float16* d = (cc < 16) ? &Ab[buf][cc*512] : &Bb[buf][(cc-16)*512];
            dma16(s + lane*8, d);
        }
    };

    // prologue: tile0 -> buf0, tile1 -> buf1; wait tile0 only (tile1 floats)
    stage(0, 0);
    stage(1, 1);
    asm volatile("s_waitcnt vmcnt(3) lgkmcnt(0)\n\ts_barrier" ::: "memory");

    f32x4 acc[4][4] = {};
    for (int kt = 0; kt < 24; ++kt) {
        const int cur = kt % 3;
        if (kt < 22) stage(kt+2, (kt+2) % 3);
        f16x8 a[4], b[4];
#pragma unroll
        for (int i = 0; i < 4; ++i)
            a[i] = *(const f16x8*)(&Ab[cur][((w>>1)*4 + i)*512] + lane*8);
#pragma unroll
        for (int j = 0; j < 4; ++j)
            b[j] = *(const f16x8*)(&Bb[cur][((w&1)*4 + j)*512] + lane*8);
#pragma unroll
        for (int i = 0; i < 4; ++i)
#pragma unroll
            for (int j = 0; j < 4; ++j)
                acc[i][j] = __builtin_amdgcn_mfma_f32_16x16x32_f16(a[i], b[j], acc[i][j], 0,0,0);
        // barrier: tile kt+1 must be complete; tile kt+2 stays in flight
        if (kt < 22)
            asm volatile("s_waitcnt vmcnt(3) lgkmcnt(0)\n\ts_barrier" ::: "memory");
        else
            asm volatile("s_waitcnt vmcnt(0) lgkmcnt(0)\n\ts_barrier" ::: "memory");
    }

    // epilogue: per-wave 32x32 transposes (buffers dead after last barrier)
    _Float16* L = &Ab[0][0] + w*1280;   // 32x40 halves per wave
#pragma unroll
    for (int i2 = 0; i2 < 2; ++i2)
#pragma unroll
        for (int j2 = 0; j2 < 2; ++j2) {
#pragma unroll
            for (int ii = 0; ii < 2; ++ii)
#pragma unroll
                for (int jj = 0; jj < 2; ++jj)
#pragma unroll
                    for (int r = 0; r < 4; ++r)
                        L[(ii*16 + quad*4 + r)*40 + jj*16 + c] =
                            (_Float16)acc[i2*2+ii][j2*2+jj][r];
#pragma unroll
            for (int ii = 0; ii < 2; ++ii) {
                const int mtg = mt0 + (w>>1)*4 + i2*2 + ii;   // 16-row unit
                if (mode == 0) {
                    f16x8 v = *(const f16x8*)(L + (ii*16 + c)*40 + quad*8);
                    const int nt32 = (nt0 + (w&1)*4)/2 + j2;  // 32-col unit
                    _Float16* dst = (nt32 < 24)
                        ? Qf + ((size_t)(mtg*24 + nt32)*64 + lane)*8
                        : Kf + ((size_t)(mtg*24 + nt32 - 24)*64 + lane)*8;
                    *(f16x8*)dst = v;
                } else {
#pragma unroll
                    for (int jj = 0; jj < 2; ++jj) {
                        f16x4 v4 = *(const f16x4*)(L + (ii*16 + c)*40 + jj*16 + quad*4);
                        const int kcu = nt0 + (w&1)*4 + j2*2 + jj;   // 16-key unit
                        *(f16x4*)(Vkt + ((size_t)kcu*48 + mtg)*256 + lane*4) = v4;
                    }
                }
            }
        }
}

// ---- fused attention v13 = EXACT v11 kernel (89.6 us, best measured) ----
// Pl stride REVERTED to 20: stride-24 measured 9.96M bank conflicts vs
// stride-20's 2.10M (12c%32 has period 8 -> lanes (c,c+8) collide on the
// same words; 10c%32 covers all 16 even residues). Empirics > my bank math.
// No XCD swizzle (v11: L2 replication across XCDs beats locality here).
// grid: 512 blocks (2/CU), 512 thr (8 waves: qi=w>>2 in {0,1}, g=w&3).
// Block = 32 q-rows (2 qt) x 512 keys; 32 subtiles of 16 keys.
// LDS 50.7 KB (Kb 24K + Ps 10.5K + Pl 15K), ~112 regs/wave -> 2 blocks/CU.
// Per iter t: [ph1(t); Ps; ph2(t-1)] A [dma K(t+1); softmax; Pl; issue vv(t)] B
__global__ __launch_bounds__(512) __attribute__((amdgpu_waves_per_eu(4)))
void attn_kernel(
    const _Float16* __restrict__ Qf, const _Float16* __restrict__ Kf,
    const _Float16* __restrict__ Vkt,
    float* __restrict__ out,          // ks==0 partial (covers all elements)
    _Float16* __restrict__ part)      // [3][4096][768] f16, ks=1..3
{
    __shared__ __attribute__((aligned(16))) _Float16 Kb[24*512];        // 24 KB
    __shared__ __attribute__((aligned(16))) float    Ps[8][336];        // 10.5 KB
    __shared__ __attribute__((aligned(16))) _Float16 Pl[2][12][16][20]; // 15 KB
    const int tid = threadIdx.x, lane = tid & 63, w = tid >> 6;
    const int c = lane & 15, quad = lane >> 4;
    const int qi = w >> 2, g = w & 3;

    const int bid = blockIdx.x;
    const int qb = bid & 63;
    const int ks = (bid >> 6) & 3;
    const int b  = bid >> 8;
    const int qrow0 = b*SEQ + qb*32;
    const int qt16  = (qrow0 >> 4) + qi;
    const int kb16  = (b*SEQ + ks*(SEQ/KSPLIT)) >> 4;
    // Ps word offset: each 16-lane group touches one contiguous 256B region
    const int psoff = quad*84 + c*4;

    // Q frags (B-operand: b[lane][j] = Q[q=lane&15][d=quad*8+j]), heads 3g..3g+2
    f16x8 qreg[6];
#pragma unroll
    for (int u = 0; u < 6; ++u)
        qreg[u] = *(const f16x8*)(Qf + ((size_t)(qt16*24 + g*6 + u)*64 + lane)*8);

    // V base for this wave's d-tile: + (t*48 + h*4)*256 per (t,h)
    const _Float16* Vb0 = Vkt + ((size_t)kb16*48 + g)*256 + (size_t)lane*4;

    // preamble: DMA K(0) (all 8 waves, 3 frags each)
#pragma unroll
    for (int u = 0; u < 3; ++u)
        dma16(Kf + ((size_t)kb16*24 + w*3 + u)*512 + lane*8, &Kb[(w*3+u)*512]);
    __syncthreads();

    f32x4 o_acc[12] = {};   // 48 AGPRs: out^T[d=g*16+quad*4+r][q=c] per head
    f16x4 vv[12];           // V tiles for ph2, issued one iter ahead
    f32x4 e3[3];            // exp2(S^T) for own 3 heads

    for (int t = 0; t < 32; ++t) {
        // ---- ph1(t): S^T = K·Q for heads 3g..3g+2, exp2 in f32 regs ----
#pragma unroll
        for (int hh = 0; hh < 3; ++hh) {
            f16x8 ka = *(const f16x8*)(&Kb[(g*6 + hh*2    )*512] + lane*8);
            f16x8 k2 = *(const f16x8*)(&Kb[(g*6 + hh*2 + 1)*512] + lane*8);
            f32x4 a = {};
            a = __builtin_amdgcn_mfma_f32_16x16x32_f16(ka, qreg[hh*2],   a, 0,0,0);
            a = __builtin_amdgcn_mfma_f32_16x16x32_f16(k2, qreg[hh*2+1], a, 0,0,0);
            // a[r] = S^T[k = quad*4+r][q = c]  (log2 domain via Wq pre-scale)
            f32x4 ee;
#pragma unroll
            for (int r = 0; r < 4; ++r) ee[r] = __builtin_amdgcn_exp2f(a[r]);
            e3[hh] = ee;
        }
        {   // 3-head partial sum -> one b128 write
            f32x4 ps;
#pragma unroll
            for (int r = 0; r < 4; ++r) ps[r] = e3[0][r] + e3[1][r] + e3[2][r];
            *(f32x4*)&Ps[qi*4+g][psoff] = ps;
        }
        // ---- ph2(t-1): 12 heads x d-tile g over 16 keys ----
        if (t > 0) {
#pragma unroll
            for (int h = 0; h < 12; ++h) {
                f16x4 pf = *(const f16x4*)&Pl[qi][h][c][quad*4];
                o_acc[h] = __builtin_amdgcn_mfma_f32_16x16x16f16(vv[h], pf, o_acc[h], 0,0,0);
            }
        }
        __syncthreads();   // A: Ps visible; Kb/Pl readers done
        // ---- DMA K(t+1) (all 8 waves; Kb single-buffered, readers drained) ----
        if (t < 31) {
#pragma unroll
            for (int u = 0; u < 3; ++u)
                dma16(Kf + ((size_t)(kb16+t+1)*24 + w*3 + u)*512 + lane*8,
                      &Kb[(w*3+u)*512]);
        }
        // ---- softmax(t): total head-sum from 4 partials, P^T -> Pl ----
        {
            f32x4 s0 = *(const f32x4*)&Ps[qi*4+0][psoff];
            f32x4 s1 = *(const f32x4*)&Ps[qi*4+1][psoff];
            f32x4 s2 = *(const f32x4*)&Ps[qi*4+2][psoff];
            f32x4 s3 = *(const f32x4*)&Ps[qi*4+3][psoff];
            f32x4 inv;
#pragma unroll
            for (int r = 0; r < 4; ++r)
                inv[r] = __builtin_amdgcn_rcpf(
                    (s0[r]+s1[r]+s2[r]+s3[r]) * 27.712812921102035f);
#pragma unroll
            for (int hh = 0; hh < 3; ++hh) {
                f16x4 pw;
#pragma unroll
                for (int r = 0; r < 4; ++r) pw[r] = (_Float16)(e3[hh][r]*inv[r]);
                *(f16x4*)&Pl[qi][g*3+hh][c][quad*4] = pw;
            }
        }
        // ---- issue all 12 V tiles for ph2(t) (consumed next iter pre-A) ----
#pragma unroll
        for (int h = 0; h < 12; ++h)
            vv[h] = *(const f16x4*)(Vb0 + ((size_t)t*48 + h*4)*256);
        __syncthreads();   // B: Pl(t) visible; K(t+1) arrived
    }
    // ---- tail: ph2(31) ----
#pragma unroll
    for (int h = 0; h < 12; ++h) {
        f16x4 pf = *(const f16x4*)&Pl[qi][h][c][quad*4];
        o_acc[h] = __builtin_amdgcn_mfma_f32_16x16x16f16(vv[h], pf, o_acc[h], 0,0,0);
    }

    // ---- epilogue: o_acc[h][r] = out[q = c][d = h*64 + g*16 + quad*4 + r] ----
    if (ks == 0) {
#pragma unroll
        for (int h = 0; h < 12; ++h)
            *(f32x4*)(out + (size_t)(qrow0 + qi*16 + c)*DIM + h*64 + g*16 + quad*4)
                = o_acc[h];
    } else {
        _Float16* dst = part + (size_t)(ks - 1) * ROWS * DIM;
#pragma unroll
        for (int h = 0; h < 12; ++h) {
            f16x4 v;
#pragma unroll
            for (int r = 0; r < 4; ++r) v[r] = (_Float16)o_acc[h][r];
            *(f16x4*)(dst + (size_t)(qrow0 + qi*16 + c)*DIM + h*64 + g*16 + quad*4) = v;
        }
    }
}

// ---- out += sum of 3 f16 partials ----
__global__ __launch_bounds__(256) void reduce_add4(
    float* __restrict__ out, const _Float16* __restrict__ part, int n4)
{
    int i = blockIdx.x * 256 + threadIdx.x;
    if (i >= n4) return;
    float4 o = reinterpret_cast<float4*>(out)[i];
    const size_t N = (size_t)ROWS * DIM;
#pragma unroll
    for (int p = 0; p < 3; ++p) {
        f16x4 v = reinterpret_cast<const f16x4*>(part + p * N)[i];
        o.x += (float)v[0]; o.y += (float)v[1]; o.z += (float)v[2]; o.w += (float)v[3];
    }
    reinterpret_cast<float4*>(out)[i] = o;
}

// ------------------------------- launch ----------------------------------
extern "C" void kernel_launch(void* const* d_in, const int* in_sizes, int n_in,
                              void* d_out, int out_size, void* d_ws, size_t ws_size,
                              hipStream_t stream)
{
    const float* x  = (const float*)d_in[0];
    const float* Wq = (const float*)d_in[1];
    const float* Wk = (const float*)d_in[2];
    const float* Wv = (const float*)d_in[3];

    _Float16* ws  = (_Float16*)d_ws;
    const size_t XS = (size_t)ROWS * DIM;   // 3145728
    const size_t WS = (size_t)DIM * DIM;    // 589824
    _Float16* xf   = ws;
    _Float16* wqf  = xf  + XS;              // wq+wk adjacent = stacked [Wq;Wk]
    _Float16* wkf  = wqf + WS;
    _Float16* wvf  = wkf + WS;
    _Float16* Qf   = wvf + WS;
    _Float16* Kf   = Qf  + XS;
    _Float16* Vkt  = Kf  + XS;
    _Float16* part = Vkt + XS;              // 3 * XS f16 partials

    cvt_all<<<2400, 256, 0, stream>>>(x, Wq, Wk, Wv, xf, wqf, wkf, wvf);
    gemm3<<<288, 512, 0, stream>>>(xf, wqf, wvf, Qf, Kf, Vkt);
    attn_kernel<<<BATCH * KSPLIT * 64, 512, 0, stream>>>(
        Qf, Kf, Vkt, (float*)d_out, part);
    reduce_add4<<<(int)(XS/4 + 255)/256, 256, 0, stream>>>(
        (float*)d_out, part, (int)(XS/4));
}

// Round 15
// 177.589 us; speedup vs baseline: 1.0120x; 1.0120x over previous
//
#include <hip/hip_runtime.h>

#define DIM 768
#define NHEADS 12
#define HDIM 64
#define BATCH 2
#define SEQ 2048
#define ROWS (BATCH*SEQ)   // 4096
#define KSPLIT 4

typedef __attribute__((ext_vector_type(8))) _Float16 f16x8;
typedef __attribute__((ext_vector_type(4))) _Float16 f16x4;
typedef __attribute__((ext_vector_type(2))) _Float16 f16x2;
typedef __attribute__((ext_vector_type(4))) float    f32x4;

// async global->LDS DMA, 16 B per lane; LDS dest must be wave-uniform base
__device__ __forceinline__ void dma16(const _Float16* g, _Float16* l) {
    __builtin_amdgcn_global_load_lds(
        (const __attribute__((address_space(1))) unsigned int*)g,
        (__attribute__((address_space(3))) unsigned int*)l, 16, 0, 0);
}

// ============================================================
// Fragment layout F(mt, kt): 16 rows x 32 cols of row-major M[R][C]:
//   frag[lane][j] = M[mt*16 + (lane&15)][kt*32 + (lane>>4)*8 + j]
// stored at dst[((mt*(C/32) + kt)*64 + lane)*8] (halves).
// V tile layout (for 16x16x16 PV MFMA): per 16-key chunk kc,
//   Vkt[((kc*48 + (h*4+dt))*64 + lane)*4] : tile[lane][j] =
//   V[d = (h*4+dt)*16 + (lane&15)][key = kc*16 + (lane>>4)*4 + j]
// ============================================================

// ---- all 4 fp32->f16 frag conversions in one launch (all have C=768) ----
// Wq is pre-scaled by log2(e): QK^T scores land in log2 domain, so the
// softmax exp is a single v_exp_f32 (2^x). Wq feeds ONLY Q. (verified v4/v5)
__global__ __launch_bounds__(256) void cvt_all(
    const float* __restrict__ x,  const float* __restrict__ wq,
    const float* __restrict__ wk, const float* __restrict__ wv,
    _Float16* __restrict__ xf,  _Float16* __restrict__ wqf,
    _Float16* __restrict__ wkf, _Float16* __restrict__ wvf)
{
    const int lane = threadIdx.x & 63;
    const int wid  = (blockIdx.x * 256 + threadIdx.x) >> 6;
    const float* src; _Float16* dst; int t;
    float sc = 1.0f;
    if (wid < 6144)      { src = x;  dst = xf;  t = wid;        }
    else if (wid < 7296) { src = wq; dst = wqf; t = wid - 6144; sc = 1.4426950408889634f; }
    else if (wid < 8448) { src = wk; dst = wkf; t = wid - 7296; }
    else                 { src = wv; dst = wvf; t = wid - 8448; }
    const int c = lane & 15, quad = lane >> 4;
    const int mt = t / 24, kt = t % 24;
    const float* p = src + (size_t)(mt*16 + c) * 768 + kt*32 + quad*8;
    float4 v0 = *(const float4*)p;
    float4 v1 = *(const float4*)(p + 4);
    f16x8 o;
    o[0]=(_Float16)(v0.x*sc); o[1]=(_Float16)(v0.y*sc); o[2]=(_Float16)(v0.z*sc); o[3]=(_Float16)(v0.w*sc);
    o[4]=(_Float16)(v1.x*sc); o[5]=(_Float16)(v1.y*sc); o[6]=(_Float16)(v1.z*sc); o[7]=(_Float16)(v1.w*sc);
    *reinterpret_cast<f16x8*>(dst + ((size_t)t * 64 + lane) * 8) = o;
}

// ---- all 3 projections, v14: single-round grid (224 <= 256 CUs) ----
// 288-block grid was 1.125 rounds (makespan 2T, 56% CU util). Re-tile:
// bid < 128: QK, 256x192 tiles (16x8 grid): C = x * [Wq;Wk]^T -> Qf/Kf.
//   Wave w: rows (w>>1)*64, cols (w&1)*96 -> acc[4][6] (96 AGPR).
// bid >= 128: V, 256x128 tiles (3x32 grid): C = Wv * x^T -> Vkt (unchanged).
// Staging: 4 units/wave (mode0: 16 A + 12 B = 28 units, waves 0-6;
// mode1: 16 A + 8 B = 24 units, waves 0-5; others stage nothing and take
// the trivial vmcnt(0) path). 3-deep buffers + counted per-wave vmcnt(4):
// tile k+1 complete at barrier, tile k+2 stays in flight (v12, verified).
// LDS (16+12)*1KB*3 = 84 KB -> 1 block/CU (grid < 256 gives that anyway).
__global__ __launch_bounds__(512) void gemm3(
    const _Float16* __restrict__ xf, const _Float16* __restrict__ wqkf,
    const _Float16* __restrict__ wvf,
    _Float16* __restrict__ Qf, _Float16* __restrict__ Kf, _Float16* __restrict__ Vkt)
{
    __shared__ _Float16 Ab[3][16*512];   // 48 KB (A: 16 row-units, 3-deep)
    __shared__ _Float16 Bb[3][12*512];   // 36 KB (B: up to 12 col-units, 3-deep)
    const int tid = threadIdx.x, lane = tid & 63, w = tid >> 6;
    const int c = lane & 15, quad = lane >> 4;

    const _Float16 *Af, *Bf;
    int mt0, nt0, mode, nunits;
    if ((int)blockIdx.x < 128) {
        int mt = blockIdx.x >> 3, nt = blockIdx.x & 7;    // 16x8 tiles
        Af = xf; Bf = wqkf; mt0 = mt*16; nt0 = nt*12; mode = 0; nunits = 28;
    } else {
        int v = blockIdx.x - 128;
        int mt = v / 32, nt = v % 32;                     // 3x32 tiles
        Af = wvf; Bf = xf; mt0 = mt*16; nt0 = nt*8; mode = 1; nunits = 24;
    }
    const bool fullw = (w*4 + 3) < nunits;   // this wave issues 4 dmas/stage

    auto stage = [&](int kt, int buf) {
#pragma unroll
        for (int u = 0; u < 4; ++u) {
            const int cc = w*4 + u;
            if (cc >= nunits) break;
            const _Float16* s = (cc < 16) ? Af + ((size_t)(mt0+cc)*24 + kt)*512
                                          : Bf + ((size_t)(nt0+cc-16)*24 + kt)*512;
            _Float16* d = (cc < 16) ? &Ab[buf][cc*512] : &Bb[buf][(cc-16)*512];
            dma16(s + lane*8, d);
        }
    };

    // prologue: tile0 -> buf0, tile1 -> buf1; wait tile0 only (tile1 floats)
    stage(0, 0);
    stage(1, 1);
    if (fullw) asm volatile("s_waitcnt vmcnt(4) lgkmcnt(0)" ::: "memory");
    else       asm volatile("s_waitcnt vmcnt(0) lgkmcnt(0)" ::: "memory");
    asm volatile("s_barrier" ::: "memory");

    if (mode == 0) {
        f32x4 acc[4][6] = {};
        for (int kt = 0; kt < 24; ++kt) {
            const int cur = kt % 3;
            if (kt < 22) stage(kt+2, (kt+2) % 3);
            f16x8 a[4], b[6];
#pragma unroll
            for (int i = 0; i < 4; ++i)
                a[i] = *(const f16x8*)(&Ab[cur][((w>>1)*4 + i)*512] + lane*8);
#pragma unroll
            for (int j = 0; j < 6; ++j)
                b[j] = *(const f16x8*)(&Bb[cur][((w&1)*6 + j)*512] + lane*8);
#pragma unroll
            for (int i = 0; i < 4; ++i)
#pragma unroll
                for (int j = 0; j < 6; ++j)
                    acc[i][j] = __builtin_amdgcn_mfma_f32_16x16x32_f16(a[i], b[j], acc[i][j], 0,0,0);
            if (kt < 22) {
                if (fullw) asm volatile("s_waitcnt vmcnt(4) lgkmcnt(0)" ::: "memory");
                else       asm volatile("s_waitcnt vmcnt(0) lgkmcnt(0)" ::: "memory");
            } else {
                asm volatile("s_waitcnt vmcnt(0) lgkmcnt(0)" ::: "memory");
            }
            asm volatile("s_barrier" ::: "memory");
        }
        // epilogue: per-wave 64x96 output as 2x3 transposed 32x32 chunks
        _Float16* L = &Ab[0][0] + w*1280;   // 32x40 halves per wave
#pragma unroll
        for (int i2 = 0; i2 < 2; ++i2)
#pragma unroll
            for (int j2 = 0; j2 < 3; ++j2) {
#pragma unroll
                for (int ii = 0; ii < 2; ++ii)
#pragma unroll
                    for (int jj = 0; jj < 2; ++jj)
#pragma unroll
                        for (int r = 0; r < 4; ++r)
                            L[(ii*16 + quad*4 + r)*40 + jj*16 + c] =
                                (_Float16)acc[i2*2+ii][j2*2+jj][r];
#pragma unroll
                for (int ii = 0; ii < 2; ++ii) {
                    const int mtg = mt0 + (w>>1)*4 + i2*2 + ii;   // 16-row unit
                    f16x8 v = *(const f16x8*)(L + (ii*16 + c)*40 + quad*8);
                    const int nt32 = (nt0 + (w&1)*6)/2 + j2;      // 32-col unit
                    _Float16* dst = (nt32 < 24)
                        ? Qf + ((size_t)(mtg*24 + nt32)*64 + lane)*8
                        : Kf + ((size_t)(mtg*24 + nt32 - 24)*64 + lane)*8;
                    *(f16x8*)dst = v;
                }
            }
    } else {
        f32x4 acc[4][4] = {};
        for (int kt = 0; kt < 24; ++kt) {
            const int cur = kt % 3;
            if (kt < 22) stage(kt+2, (kt+2) % 3);
            f16x8 a[4], b[4];
#pragma unroll
            for (int i = 0; i < 4; ++i)
                a[i] = *(const f16x8*)(&Ab[cur][((w>>1)*4 + i)*512] + lane*8);
#pragma unroll
            for (int j = 0; j < 4; ++j)
                b[j] = *(const f16x8*)(&Bb[cur][((w&1)*4 + j)*512] + lane*8);
#pragma unroll
            for (int i = 0; i < 4; ++i)
#pragma unroll
                for (int j = 0; j < 4; ++j)
                    acc[i][j] = __builtin_amdgcn_mfma_f32_16x16x32_f16(a[i], b[j], acc[i][j], 0,0,0);
            if (kt < 22) {
                if (fullw) asm volatile("s_waitcnt vmcnt(4) lgkmcnt(0)" ::: "memory");
                else       asm volatile("s_waitcnt vmcnt(0) lgkmcnt(0)" ::: "memory");
            } else {
                asm volatile("s_waitcnt vmcnt(0) lgkmcnt(0)" ::: "memory");
            }
            asm volatile("s_barrier" ::: "memory");
        }
        // epilogue: per-wave 32x32 transposes -> Vkt tiles (verified path)
        _Float16* L = &Ab[0][0] + w*1280;   // 32x40 halves per wave
#pragma unroll
        for (int i2 = 0; i2 < 2; ++i2)
#pragma unroll
            for (int j2 = 0; j2 < 2; ++j2) {
#pragma unroll
                for (int ii = 0; ii < 2; ++ii)
#pragma unroll
                    for (int jj = 0; jj < 2; ++jj)
#pragma unroll
                        for (int r = 0; r < 4; ++r)
                            L[(ii*16 + quad*4 + r)*40 + jj*16 + c] =
                                (_Float16)acc[i2*2+ii][j2*2+jj][r];
#pragma unroll
                for (int ii = 0; ii < 2; ++ii) {
                    const int mtg = mt0 + (w>>1)*4 + i2*2 + ii;   // 16-row unit
#pragma unroll
                    for (int jj = 0; jj < 2; ++jj) {
                        f16x4 v4 = *(const f16x4*)(L + (ii*16 + c)*40 + jj*16 + quad*4);
                        const int kcu = nt0 + (w&1)*4 + j2*2 + jj;   // 16-key unit
                        *(f16x4*)(Vkt + ((size_t)kcu*48 + mtg)*256 + lane*4) = v4;
                    }
                }
            }
    }
}

// ---- fused attention = EXACT v11/v13 kernel (87.5-89.6 us, best measured) ----
// Pl stride 20 (stride-24 measured 4.7x MORE conflicts); no XCD swizzle
// (L2 replication across XCDs beats locality for the L2-BW-bound V stream).
// grid: 512 blocks (2/CU), 512 thr (8 waves: qi=w>>2 in {0,1}, g=w&3).
// Block = 32 q-rows (2 qt) x 512 keys; 32 subtiles of 16 keys.
// LDS 50.7 KB (Kb 24K + Ps 10.5K + Pl 15K), ~112 regs/wave -> 2 blocks/CU.
// Per iter t: [ph1(t); Ps; ph2(t-1)] A [dma K(t+1); softmax; Pl; issue vv(t)] B
__global__ __launch_bounds__(512) __attribute__((amdgpu_waves_per_eu(4)))
void attn_kernel(
    const _Float16* __restrict__ Qf, const _Float16* __restrict__ Kf,
    const _Float16* __restrict__ Vkt,
    float* __restrict__ out,          // ks==0 partial (covers all elements)
    _Float16* __restrict__ part)      // [3][4096][768] f16, ks=1..3
{
    __shared__ __attribute__((aligned(16))) _Float16 Kb[24*512];        // 24 KB
    __shared__ __attribute__((aligned(16))) float    Ps[8][336];        // 10.5 KB
    __shared__ __attribute__((aligned(16))) _Float16 Pl[2][12][16][20]; // 15 KB
    const int tid = threadIdx.x, lane = tid & 63, w = tid >> 6;
    const int c = lane & 15, quad = lane >> 4;
    const int qi = w >> 2, g = w & 3;

    const int bid = blockIdx.x;
    const int qb = bid & 63;
    const int ks = (bid >> 6) & 3;
    const int b  = bid >> 8;
    const int qrow0 = b*SEQ + qb*32;
    const int qt16  = (qrow0 >> 4) + qi;
    const int kb16  = (b*SEQ + ks*(SEQ/KSPLIT)) >> 4;
    // Ps word offset: each 16-lane group touches one contiguous 256B region
    const int psoff = quad*84 + c*4;

    // Q frags (B-operand: b[lane][j] = Q[q=lane&15][d=quad*8+j]), heads 3g..3g+2
    f16x8 qreg[6];
#pragma unroll
    for (int u = 0; u < 6; ++u)
        qreg[u] = *(const f16x8*)(Qf + ((size_t)(qt16*24 + g*6 + u)*64 + lane)*8);

    // V base for this wave's d-tile: + (t*48 + h*4)*256 per (t,h)
    const _Float16* Vb0 = Vkt + ((size_t)kb16*48 + g)*256 + (size_t)lane*4;

    // preamble: DMA K(0) (all 8 waves, 3 frags each)
#pragma unroll
    for (int u = 0; u < 3; ++u)
        dma16(Kf + ((size_t)kb16*24 + w*3 + u)*512 + lane*8, &Kb[(w*3+u)*512]);
    __syncthreads();

    f32x4 o_acc[12] = {};   // 48 AGPRs: out^T[d=g*16+quad*4+r][q=c] per head
    f16x4 vv[12];           // V tiles for ph2, issued one iter ahead
    f32x4 e3[3];            // exp2(S^T) for own 3 heads

    for (int t = 0; t < 32; ++t) {
        // ---- ph1(t): S^T = K·Q for heads 3g..3g+2, exp2 in f32 regs ----
#pragma unroll
        for (int hh = 0; hh < 3; ++hh) {
            f16x8 ka = *(const f16x8*)(&Kb[(g*6 + hh*2    )*512] + lane*8);
            f16x8 k2 = *(const f16x8*)(&Kb[(g*6 + hh*2 + 1)*512] + lane*8);
            f32x4 a = {};
            a = __builtin_amdgcn_mfma_f32_16x16x32_f16(ka, qreg[hh*2],   a, 0,0,0);
            a = __builtin_amdgcn_mfma_f32_16x16x32_f16(k2, qreg[hh*2+1], a, 0,0,0);
            // a[r] = S^T[k = quad*4+r][q = c]  (log2 domain via Wq pre-scale)
            f32x4 ee;
#pragma unroll
            for (int r = 0; r < 4; ++r) ee[r] = __builtin_amdgcn_exp2f(a[r]);
            e3[hh] = ee;
        }
        {   // 3-head partial sum -> one b128 write
            f32x4 ps;
#pragma unroll
            for (int r = 0; r < 4; ++r) ps[r] = e3[0][r] + e3[1][r] + e3[2][r];
            *(f32x4*)&Ps[qi*4+g][psoff] = ps;
        }
        // ---- ph2(t-1): 12 heads x d-tile g over 16 keys ----
        if (t > 0) {
#pragma unroll
            for (int h = 0; h < 12; ++h) {
                f16x4 pf = *(const f16x4*)&Pl[qi][h][c][quad*4];
                o_acc[h] = __builtin_amdgcn_mfma_f32_16x16x16f16(vv[h], pf, o_acc[h], 0,0,0);
            }
        }
        __syncthreads();   // A: Ps visible; Kb/Pl readers done
        // ---- DMA K(t+1) (all 8 waves; Kb single-buffered, readers drained) ----
        if (t < 31) {
#pragma unroll
            for (int u = 0; u < 3; ++u)
                dma16(Kf + ((size_t)(kb16+t+1)*24 + w*3 + u)*512 + lane*8,
                      &Kb[(w*3+u)*512]);
        }
        // ---- softmax(t): total head-sum from 4 partials, P^T -> Pl ----
        {
            f32x4 s0 = *(const f32x4*)&Ps[qi*4+0][psoff];
            f32x4 s1 = *(const f32x4*)&Ps[qi*4+1][psoff];
            f32x4 s2 = *(const f32x4*)&Ps[qi*4+2][psoff];
            f32x4 s3 = *(const f32x4*)&Ps[qi*4+3][psoff];
            f32x4 inv;
#pragma unroll
            for (int r = 0; r < 4; ++r)
                inv[r] = __builtin_amdgcn_rcpf(
                    (s0[r]+s1[r]+s2[r]+s3[r]) * 27.712812921102035f);
#pragma unroll
            for (int hh = 0; hh < 3; ++hh) {
                f16x4 pw;
#pragma unroll
                for (int r = 0; r < 4; ++r) pw[r] = (_Float16)(e3[hh][r]*inv[r]);
                *(f16x4*)&Pl[qi][g*3+hh][c][quad*4] = pw;
            }
        }
        // ---- issue all 12 V tiles for ph2(t) (consumed next iter pre-A) ----
#pragma unroll
        for (int h = 0; h < 12; ++h)
            vv[h] = *(const f16x4*)(Vb0 + ((size_t)t*48 + h*4)*256);
        __syncthreads();   // B: Pl(t) visible; K(t+1) arrived
    }
    // ---- tail: ph2(31) ----
#pragma unroll
    for (int h = 0; h < 12; ++h) {
        f16x4 pf = *(const f16x4*)&Pl[qi][h][c][quad*4];
        o_acc[h] = __builtin_amdgcn_mfma_f32_16x16x16f16(vv[h], pf, o_acc[h], 0,0,0);
    }

    // ---- epilogue: o_acc[h][r] = out[q = c][d = h*64 + g*16 + quad*4 + r] ----
    if (ks == 0) {
#pragma unroll
        for (int h = 0; h < 12; ++h)
            *(f32x4*)(out + (size_t)(qrow0 + qi*16 + c)*DIM + h*64 + g*16 + quad*4)
                = o_acc[h];
    } else {
        _Float16* dst = part + (size_t)(ks - 1) * ROWS * DIM;
#pragma unroll
        for (int h = 0; h < 12; ++h) {
            f16x4 v;
#pragma unroll
            for (int r = 0; r < 4; ++r) v[r] = (_Float16)o_acc[h][r];
            *(f16x4*)(dst + (size_t)(qrow0 + qi*16 + c)*DIM + h*64 + g*16 + quad*4) = v;
        }
    }
}

// ---- out += sum of 3 f16 partials ----
__global__ __launch_bounds__(256) void reduce_add4(
    float* __restrict__ out, const _Float16* __restrict__ part, int n4)
{
    int i = blockIdx.x * 256 + threadIdx.x;
    if (i >= n4) return;
    float4 o = reinterpret_cast<float4*>(out)[i];
    const size_t N = (size_t)ROWS * DIM;
#pragma unroll
    for (int p = 0; p < 3; ++p) {
        f16x4 v = reinterpret_cast<const f16x4*>(part + p * N)[i];
        o.x += (float)v[0]; o.y += (float)v[1]; o.z += (float)v[2]; o.w += (float)v[3];
    }
    reinterpret_cast<float4*>(out)[i] = o;
}

// ------------------------------- launch ----------------------------------
extern "C" void kernel_launch(void* const* d_in, const int* in_sizes, int n_in,
                              void* d_out, int out_size, void* d_ws, size_t ws_size,
                              hipStream_t stream)
{
    const float* x  = (const float*)d_in[0];
    const float* Wq = (const float*)d_in[1];
    const float* Wk = (const float*)d_in[2];
    const float* Wv = (const float*)d_in[3];

    _Float16* ws  = (_Float16*)d_ws;
    const size_t XS = (size_t)ROWS * DIM;   // 3145728
    const size_t WS = (size_t)DIM * DIM;    // 589824
    _Float16* xf   = ws;
    _Float16* wqf  = xf  + XS;              // wq+wk adjacent = stacked [Wq;Wk]
    _Float16* wkf  = wqf + WS;
    _Float16* wvf  = wkf + WS;
    _Float16* Qf   = wvf + WS;
    _Float16* Kf   = Qf  + XS;
    _Float16* Vkt  = Kf  + XS;
    _Float16* part = Vkt + XS;              // 3 * XS f16 partials

    cvt_all<<<2400, 256, 0, stream>>>(x, Wq, Wk, Wv, xf, wqf, wkf, wvf);
    gemm3<<<224, 512, 0, stream>>>(xf, wqf, wvf, Qf, Kf, Vkt);
    attn_kernel<<<BATCH * KSPLIT * 64, 512, 0, stream>>>(
        Qf, Kf, Vkt, (float*)d_out, part);
    reduce_add4<<<(int)(XS/4 + 255)/256, 256, 0, stream>>>(
        (float*)d_out, part, (int)(XS/4));
}